// Round 23
// baseline (347.432 us; speedup 1.0000x reference)
//
#include <hip/hip_runtime.h>
#include <hip/hip_bf16.h>

#define NN 50000
#define EE 800000
#define ETOT 850000
#define BB 512
#define CAP 64     // bucket capacity per node; Poisson(17) => P(deg>63) ~ 1e-18

typedef __hip_bfloat16 bf16;
typedef __attribute__((ext_vector_type(8))) __bf16 v8bf;
typedef __attribute__((ext_vector_type(4))) float f32x4;

__device__ __forceinline__ float lo2f(unsigned int u) {
    return __uint_as_float(u << 16);
}
__device__ __forceinline__ float hi2f(unsigned int u) {
    return __uint_as_float(u & 0xffff0000u);
}
__device__ __forceinline__ float us2f(unsigned short u) {
    return __uint_as_float(((unsigned int)u) << 16);
}
__device__ __forceinline__ unsigned short f2bfbits(float f) {
    bf16 h = __float2bfloat16(f);
    return *reinterpret_cast<unsigned short*>(&h);
}
__device__ __forceinline__ float lrelu_exp(float ev) {
    ev = ev > 0.f ? ev : 0.2f * ev;
    return __expf(fminf(ev, 80.f));
}

// ---------------- prep: weight transpose+cvt AND zero deg ----------------
__global__ void k_prep(const float* __restrict__ W1, const float* __restrict__ W2,
                       bf16* __restrict__ wt1, bf16* __restrict__ wt2,
                       int* __restrict__ deg) {
    int idx = blockIdx.x * blockDim.x + threadIdx.x;  // 65536 threads
    if (idx < 256 * 128) {
        int c = idx >> 7, k = idx & 127;
        wt1[idx] = __float2bfloat16(W1[k * 256 + c]);
    } else {
        int j = idx - 256 * 128;
        int c = j >> 8, k = j & 255;
        wt2[j] = __float2bfloat16(W2[k * 128 + c]);
    }
    if (idx < NN) deg[idx] = 0;
}

// ---------------- bucket scatter: all edges incl. self-loops (R20 proven) ----------------
__global__ void k_scatter(const int* __restrict__ srcArr, const int* __restrict__ dstArr,
                          int* __restrict__ deg, int* __restrict__ csrc) {
    int e = blockIdx.x * blockDim.x + threadIdx.x;
    if (e >= ETOT) return;
    int d, s;
    if (e < EE) { d = dstArr[e]; s = srcArr[e]; }
    else        { d = e - EE;    s = d; }
    d = min(max(d, 0), NN - 1);
    s = min(max(s, 0), NN - 1);
    int p = atomicAdd(&deg[d], 1);
    if (p < CAP) csrc[d * CAP + p] = s;
}

// ---------------- Layer 1 GEMM via MFMA: 32 nodes/block (proven R12) ----------------
__global__ __launch_bounds__(256, 2)
void k_gemm1(const float* __restrict__ x, const bf16* __restrict__ wt1,
             const float* __restrict__ aw_s, const float* __restrict__ aw_d,
             bf16* __restrict__ h1, float* __restrict__ as1,
             float* __restrict__ ad1) {
    int n0 = blockIdx.x * 32;
    int t = threadIdx.x;
    __shared__ bf16 xs[32 * 136];
    for (int i = 0; i < 4; i++) {
        int idx = t + 256 * i;
        int r = idx >> 5, c4 = idx & 31;
        float4 v = make_float4(0.f, 0.f, 0.f, 0.f);
        if (n0 + r < NN) v = *(const float4*)(x + (size_t)(n0 + r) * 128 + c4 * 4);
        ushort4 o;
        o.x = f2bfbits(v.x); o.y = f2bfbits(v.y);
        o.z = f2bfbits(v.z); o.w = f2bfbits(v.w);
        *(ushort4*)(&xs[r * 136 + c4 * 4]) = o;
    }
    __syncthreads();

    int wv = t >> 6, lane = t & 63;
    int q = lane >> 4, r16 = lane & 15;
    int rowBase = (wv & 1) * 16;
    int colBase = (wv >> 1) * 128;

    f32x4 acc[8];
#pragma unroll
    for (int ct = 0; ct < 8; ct++) acc[ct] = (f32x4){0.f, 0.f, 0.f, 0.f};

#pragma unroll
    for (int kt = 0; kt < 4; kt++) {
        v8bf va = *(const v8bf*)(&xs[(rowBase + r16) * 136 + kt * 32 + q * 8]);
#pragma unroll
        for (int ct = 0; ct < 8; ct++) {
            v8bf vb = *(const v8bf*)(wt1 + (size_t)(colBase + ct * 16 + r16) * 128 + kt * 32 + q * 8);
            acc[ct] = __builtin_amdgcn_mfma_f32_16x16x32_bf16(va, vb, acc[ct], 0, 0, 0);
        }
    }

    float wsv[8], wdv[8];
#pragma unroll
    for (int ct = 0; ct < 8; ct++) {
        int col = colBase + ct * 16 + r16;
        wsv[ct] = aw_s[col];
        wdv[ct] = aw_d[col];
    }

    float ps[4][2], pd[4][2];
#pragma unroll
    for (int reg = 0; reg < 4; reg++) {
        ps[reg][0] = 0.f; ps[reg][1] = 0.f;
        pd[reg][0] = 0.f; pd[reg][1] = 0.f;
    }

#pragma unroll
    for (int reg = 0; reg < 4; reg++) {
        int node = n0 + rowBase + q * 4 + reg;
        bool ok = node < NN;
#pragma unroll
        for (int ct = 0; ct < 8; ct++) {
            float v = acc[ct][reg];
            if (ok) h1[(size_t)node * 256 + colBase + ct * 16 + r16] = __float2bfloat16(v);
            ps[reg][ct >> 2] += v * wsv[ct];
            pd[reg][ct >> 2] += v * wdv[ct];
        }
    }

#pragma unroll
    for (int reg = 0; reg < 4; reg++) {
        int node = n0 + rowBase + q * 4 + reg;
        bool ok = node < NN;
#pragma unroll
        for (int lh = 0; lh < 2; lh++) {
            float a = ps[reg][lh], b = pd[reg][lh];
            for (int mask = 1; mask <= 8; mask <<= 1) {
                a += __shfl_xor(a, mask);
                b += __shfl_xor(b, mask);
            }
            if (r16 == 0 && ok) {
                int head = (wv >> 1) * 2 + lh;
                as1[node * 4 + head] = a;
                ad1[node * 4 + head] = b;
            }
        }
    }
}

// ---------------- Layer 1 gather: 2 col-slices/node, single chunk, 32-bit offsets (R20 proven) ----------------
__global__ void k_gather1(const int* __restrict__ csrc, const int* __restrict__ deg,
                          const bf16* __restrict__ h1, const float* __restrict__ as1,
                          const float* __restrict__ ad1, const float* __restrict__ b1,
                          bf16* __restrict__ x2) {
    int bid = blockIdx.x;
    int n = bid >> 1, slice = bid & 1;
    int t = threadIdx.x;        // 0..63
    int lh = t >> 5;            // local head (0/1)
    int cnt = min(deg[n], CAP);
    float2 ad = *(const float2*)&ad1[n * 4 + slice * 2];
    __shared__ unsigned int ls[CAP];   // pre-scaled byte offsets (s*512)
    __shared__ float la[CAP * 2];
    const char* h1c = (const char*)h1;
    unsigned int tconst = (unsigned int)(slice * 128 + t * 2) * 2;
    if (t < cnt) {
        int s = csrc[n * CAP + t];
        s = min(max(s, 0), NN - 1);
        ls[t] = (unsigned int)s << 9;
        float2 as = *(const float2*)&as1[s * 4 + slice * 2];
        la[t * 2 + 0] = lrelu_exp(as.x + ad.x);
        la[t * 2 + 1] = lrelu_exp(as.y + ad.y);
    }
    __syncthreads();
    float a0 = 0.f, a1 = 0.f, ssum = 0.f;
    int j = 0;
    for (; j + 3 < cnt; j += 4) {
        unsigned int o0 = ls[j] + tconst, o1 = ls[j + 1] + tconst;
        unsigned int o2 = ls[j + 2] + tconst, o3 = ls[j + 3] + tconst;
        float A0 = la[j * 2 + lh], A1 = la[j * 2 + 2 + lh];
        float A2 = la[j * 2 + 4 + lh], A3 = la[j * 2 + 6 + lh];
        unsigned int u0 = *(const unsigned int*)(h1c + o0);
        unsigned int u1 = *(const unsigned int*)(h1c + o1);
        unsigned int u2 = *(const unsigned int*)(h1c + o2);
        unsigned int u3 = *(const unsigned int*)(h1c + o3);
        ssum += (A0 + A1) + (A2 + A3);
        a0 = fmaf(A0, lo2f(u0), a0); a0 = fmaf(A1, lo2f(u1), a0);
        a0 = fmaf(A2, lo2f(u2), a0); a0 = fmaf(A3, lo2f(u3), a0);
        a1 = fmaf(A0, hi2f(u0), a1); a1 = fmaf(A1, hi2f(u1), a1);
        a1 = fmaf(A2, hi2f(u2), a1); a1 = fmaf(A3, hi2f(u3), a1);
    }
    for (; j < cnt; j++) {
        unsigned int o0 = ls[j] + tconst;
        float A0 = la[j * 2 + lh];
        unsigned int u0 = *(const unsigned int*)(h1c + o0);
        ssum += A0;
        a0 = fmaf(A0, lo2f(u0), a0);
        a1 = fmaf(A0, hi2f(u0), a1);
    }
    float inv = 1.f / fmaxf(ssum, 1e-35f);
    int c = slice * 128 + t * 2;
    float r0 = a0 * inv + b1[c + 0];
    float r1 = a1 * inv + b1[c + 1];
    r0 = r0 > 0.f ? r0 : (__expf(r0) - 1.f);
    r1 = r1 > 0.f ? r1 : (__expf(r1) - 1.f);
    unsigned int packed = (unsigned int)f2bfbits(r0) | ((unsigned int)f2bfbits(r1) << 16);
    *(unsigned int*)((unsigned short*)x2 + (size_t)n * 256 + c) = packed;
}

// ---------------- Layer 2 GEMM via MFMA: 32 nodes/block (R18) ----------------
__global__ __launch_bounds__(256, 2)
void k_gemm2(const bf16* __restrict__ x2, const bf16* __restrict__ wt2,
             const float* __restrict__ aw_s, const float* __restrict__ aw_d,
             bf16* __restrict__ h2, float* __restrict__ as2,
             float* __restrict__ ad2) {
    int n0 = blockIdx.x * 32;
    int t = threadIdx.x;
    __shared__ bf16 xs[32 * 264];
    __shared__ float psPart[32][2];
    __shared__ float pdPart[32][2];
    for (int i = 0; i < 4; i++) {
        int idx = t + 256 * i;
        int r = idx >> 5, c8 = idx & 31;
        uint4 v;
        if (n0 + r < NN) v = *(const uint4*)(x2 + (size_t)(n0 + r) * 256 + c8 * 8);
        else             v = make_uint4(0, 0, 0, 0);
        *(uint4*)(&xs[r * 264 + c8 * 8]) = v;
    }
    __syncthreads();

    int wv = t >> 6, lane = t & 63;
    int q = lane >> 4, r16 = lane & 15;
    int rowBase = (wv & 1) * 16;
    int colBase = (wv >> 1) * 64;

    f32x4 acc[4];
#pragma unroll
    for (int ct = 0; ct < 4; ct++) acc[ct] = (f32x4){0.f, 0.f, 0.f, 0.f};

#pragma unroll
    for (int kt = 0; kt < 8; kt++) {
        v8bf va = *(const v8bf*)(&xs[(rowBase + r16) * 264 + kt * 32 + q * 8]);
#pragma unroll
        for (int ct = 0; ct < 4; ct++) {
            v8bf vb = *(const v8bf*)(wt2 + (size_t)(colBase + ct * 16 + r16) * 256 + kt * 32 + q * 8);
            acc[ct] = __builtin_amdgcn_mfma_f32_16x16x32_bf16(va, vb, acc[ct], 0, 0, 0);
        }
    }

    float wsv[4], wdv[4];
#pragma unroll
    for (int ct = 0; ct < 4; ct++) {
        int col = colBase + ct * 16 + r16;
        wsv[ct] = aw_s[col];
        wdv[ct] = aw_d[col];
    }

#pragma unroll
    for (int reg = 0; reg < 4; reg++) {
        int node = n0 + rowBase + q * 4 + reg;
        bool ok = node < NN;
        float ps = 0.f, pd = 0.f;
#pragma unroll
        for (int ct = 0; ct < 4; ct++) {
            float v = acc[ct][reg];
            if (ok) h2[(size_t)node * 128 + colBase + ct * 16 + r16] = __float2bfloat16(v);
            ps += v * wsv[ct];
            pd += v * wdv[ct];
        }
        for (int mask = 1; mask <= 8; mask <<= 1) {
            ps += __shfl_xor(ps, mask);
            pd += __shfl_xor(pd, mask);
        }
        if (r16 == 0) {
            int li = rowBase + q * 4 + reg;
            psPart[li][wv >> 1] = ps;
            pdPart[li][wv >> 1] = pd;
        }
    }
    __syncthreads();
    if (t < 32) {
        int node = n0 + t;
        if (node < NN) {
            as2[node] = psPart[t][0] + psPart[t][1];
            ad2[node] = pdPart[t][0] + pdPart[t][1];
        }
    }
}

// ---------------- Layer 2 gather: single chunk, 32-bit offsets, bf16 store ----------------
__global__ void k_gather2(const int* __restrict__ csrc, const int* __restrict__ deg,
                          const bf16* __restrict__ h2, const float* __restrict__ as2,
                          const float* __restrict__ ad2, const float* __restrict__ b2,
                          bf16* __restrict__ hf) {
    int n = blockIdx.x;
    int t = threadIdx.x;        // 0..63
    int cnt = min(deg[n], CAP);
    float adn = ad2[n];
    __shared__ unsigned int ls[CAP];   // pre-scaled byte offsets (s*256)
    __shared__ float la[CAP];
    const char* h2c = (const char*)h2;
    unsigned int tconst = (unsigned int)t * 4;
    if (t < cnt) {
        int s = csrc[n * CAP + t];
        s = min(max(s, 0), NN - 1);
        ls[t] = (unsigned int)s << 8;
        la[t] = lrelu_exp(as2[s] + adn);
    }
    __syncthreads();
    float a0 = 0.f, a1 = 0.f, ssum = 0.f;
    int j = 0;
    for (; j + 3 < cnt; j += 4) {
        unsigned int o0 = ls[j] + tconst, o1 = ls[j + 1] + tconst;
        unsigned int o2 = ls[j + 2] + tconst, o3 = ls[j + 3] + tconst;
        float A0 = la[j], A1 = la[j + 1], A2 = la[j + 2], A3 = la[j + 3];
        unsigned int u0 = *(const unsigned int*)(h2c + o0);
        unsigned int u1 = *(const unsigned int*)(h2c + o1);
        unsigned int u2 = *(const unsigned int*)(h2c + o2);
        unsigned int u3 = *(const unsigned int*)(h2c + o3);
        ssum += (A0 + A1) + (A2 + A3);
        a0 = fmaf(A0, lo2f(u0), a0); a0 = fmaf(A1, lo2f(u1), a0);
        a0 = fmaf(A2, lo2f(u2), a0); a0 = fmaf(A3, lo2f(u3), a0);
        a1 = fmaf(A0, hi2f(u0), a1); a1 = fmaf(A1, hi2f(u1), a1);
        a1 = fmaf(A2, hi2f(u2), a1); a1 = fmaf(A3, hi2f(u3), a1);
    }
    for (; j < cnt; j++) {
        unsigned int o0 = ls[j] + tconst;
        float A0 = la[j];
        unsigned int u0 = *(const unsigned int*)(h2c + o0);
        ssum += A0;
        a0 = fmaf(A0, lo2f(u0), a0);
        a1 = fmaf(A0, hi2f(u0), a1);
    }
    float inv = 1.f / fmaxf(ssum, 1e-35f);
    int c = t * 2;
    float r0 = a0 * inv + b2[c + 0];
    float r1 = a1 * inv + b2[c + 1];
    r0 = r0 > 0.f ? r0 : (__expf(r0) - 1.f);
    r1 = r1 > 0.f ? r1 : (__expf(r1) - 1.f);
    unsigned int packed = (unsigned int)f2bfbits(r0) | ((unsigned int)f2bfbits(r1) << 16);
    *(unsigned int*)((unsigned short*)hf + (size_t)n * 128 + c) = packed;
}

// ---------------- fused mean-pool + linear + sigmoid (batch SORTED; bf16 input) ----------------
__global__ void k_pool(const bf16* __restrict__ hf, const int* __restrict__ batch,
                       const float* __restrict__ Wl, const float* __restrict__ bl,
                       float* __restrict__ out) {
    int b = blockIdx.x;   // 0..511
    int t = threadIdx.x;  // 0..127
    int lo = 0, hi = NN;
    while (lo < hi) { int m = (lo + hi) >> 1; if (batch[m] < b) lo = m + 1; else hi = m; }
    int start = lo;
    int lo2 = start, hi2 = NN;
    while (lo2 < hi2) { int m = (lo2 + hi2) >> 1; if (batch[m] < b + 1) lo2 = m + 1; else hi2 = m; }
    int end = lo2;
    const unsigned short* hu = (const unsigned short*)hf;
    float sum = 0.f;
    for (int n = start; n < end; n++) sum += us2f(hu[(size_t)n * 128 + t]);
    int c = end - start;
    float g = sum / (float)(c > 0 ? c : 1);
    float p = g * Wl[t];
    for (int o = 32; o > 0; o >>= 1) p += __shfl_down(p, o);
    __shared__ float red[2];
    if ((t & 63) == 0) red[t >> 6] = p;
    __syncthreads();
    if (t == 0) {
        float acc = red[0] + red[1] + bl[0];
        out[b] = 1.f / (1.f + __expf(-acc));
    }
}

extern "C" void kernel_launch(void* const* d_in, const int* in_sizes, int n_in,
                              void* d_out, int out_size, void* d_ws, size_t ws_size,
                              hipStream_t stream) {
    const float* x = (const float*)d_in[0];
    const int* ei = (const int*)d_in[1];
    const int* batch = (const int*)d_in[2];
    const float* W1 = (const float*)d_in[3];
    const float* aw_s1 = (const float*)d_in[4];
    const float* aw_d1 = (const float*)d_in[5];
    const float* b1 = (const float*)d_in[6];
    const float* W2 = (const float*)d_in[7];
    const float* aw_s2 = (const float*)d_in[8];
    const float* aw_d2 = (const float*)d_in[9];
    const float* b2 = (const float*)d_in[10];
    const float* Wl = (const float*)d_in[11];
    const float* bl = (const float*)d_in[12];
    const int* srcArr = ei;
    const int* dstArr = ei + EE;

    char* w = (char*)d_ws;
    size_t off = 0;
    auto alloc = [&](size_t bytes) -> void* {
        void* p = (void*)(w + off);
        off = (off + bytes + 255) & ~(size_t)255;
        return p;
    };
    bf16* bufA = (bf16*)alloc((size_t)NN * 256 * 2);   // h1; later h2
    bf16* bufB = (bf16*)alloc((size_t)NN * 256 * 2);   // x2; later hf (bf16 [NN,128])
    int* csrc = (int*)alloc((size_t)NN * CAP * 4);     // 12.8 MB
    float* as1 = (float*)alloc((size_t)NN * 4 * 4);
    float* ad1 = (float*)alloc((size_t)NN * 4 * 4);
    float* as2 = (float*)alloc((size_t)NN * 4);
    float* ad2 = (float*)alloc((size_t)NN * 4);
    int* deg = (int*)alloc((size_t)NN * 4);
    bf16* wt1 = (bf16*)alloc((size_t)256 * 128 * 2);
    bf16* wt2 = (bf16*)alloc((size_t)128 * 256 * 2);
    (void)ws_size;

    k_prep<<<256, 256, 0, stream>>>(W1, W2, wt1, wt2, deg);
    k_scatter<<<(ETOT + 255) / 256, 256, 0, stream>>>(srcArr, dstArr, deg, csrc);

    bf16* h1 = bufA;
    bf16* x2 = bufB;
    k_gemm1<<<(NN + 31) / 32, 256, 0, stream>>>(x, wt1, aw_s1, aw_d1, h1, as1, ad1);
    k_gather1<<<NN * 2, 64, 0, stream>>>(csrc, deg, h1, as1, ad1, b1, x2);

    bf16* h2 = bufA;  // h1 dead after gather1
    k_gemm2<<<(NN + 31) / 32, 256, 0, stream>>>(x2, wt2, aw_s2, aw_d2, h2, as2, ad2);

    bf16* hf = bufB;  // x2 dead after gemm2
    k_gather2<<<NN, 64, 0, stream>>>(csrc, deg, h2, as2, ad2, b2, hf);

    k_pool<<<BB, 128, 0, stream>>>(hf, batch, Wl, bl, (float*)d_out);
}

// Round 27
// 327.632 us; speedup vs baseline: 1.0604x; 1.0604x over previous
//
#include <hip/hip_runtime.h>
#include <hip/hip_bf16.h>

#define NN 50000
#define EE 800000
#define ETOT 850000
#define BB 512
#define CAP 64     // bucket capacity per node; Poisson(17) => P(deg>63) ~ 1e-18
#define NPART 8    // dst-range partitions (one per XCD under round-robin dispatch)
#define DPP 6250   // nodes per partition = NN/NPART

typedef __hip_bfloat16 bf16;
typedef __attribute__((ext_vector_type(8))) __bf16 v8bf;
typedef __attribute__((ext_vector_type(4))) float f32x4;

__device__ __forceinline__ float lo2f(unsigned int u) {
    return __uint_as_float(u << 16);
}
__device__ __forceinline__ float hi2f(unsigned int u) {
    return __uint_as_float(u & 0xffff0000u);
}
__device__ __forceinline__ float us2f(unsigned short u) {
    return __uint_as_float(((unsigned int)u) << 16);
}
__device__ __forceinline__ unsigned short f2bfbits(float f) {
    bf16 h = __float2bfloat16(f);
    return *reinterpret_cast<unsigned short*>(&h);
}
__device__ __forceinline__ float lrelu_exp(float ev) {
    ev = ev > 0.f ? ev : 0.2f * ev;
    return __expf(fminf(ev, 80.f));
}

// ---------------- prep: weight transpose+cvt AND zero deg ----------------
__global__ void k_prep(const float* __restrict__ W1, const float* __restrict__ W2,
                       bf16* __restrict__ wt1, bf16* __restrict__ wt2,
                       int* __restrict__ deg) {
    int idx = blockIdx.x * blockDim.x + threadIdx.x;  // 65536 threads
    if (idx < 256 * 128) {
        int c = idx >> 7, k = idx & 127;
        wt1[idx] = __float2bfloat16(W1[k * 256 + c]);
    } else {
        int j = idx - 256 * 128;
        int c = j >> 8, k = j & 255;
        wt2[j] = __float2bfloat16(W2[k * 128 + c]);
    }
    if (idx < NN) deg[idx] = 0;
}

// ---------------- XCD-partitioned bucket scatter ----------------
// part = blockIdx&7 -> one XCD under round-robin dispatch; each partition owns
// dst range [part*DPP, (part+1)*DPP): deg/csrc lines stay XCD-local.
__global__ void k_scatter(const int* __restrict__ srcArr, const int* __restrict__ dstArr,
                          int* __restrict__ deg, int* __restrict__ csrc) {
    int part = blockIdx.x & (NPART - 1);
    int e = (blockIdx.x >> 3) * 256 + threadIdx.x;
    if (e >= ETOT) return;
    int d, s;
    if (e < EE) { d = dstArr[e]; s = srcArr[e]; }
    else        { d = e - EE;    s = d; }
    d = min(max(d, 0), NN - 1);
    s = min(max(s, 0), NN - 1);
    int lo = part * DPP;
    if (d >= lo && d < lo + DPP) {
        int p = atomicAdd(&deg[d], 1);
        if (p < CAP) csrc[d * CAP + p] = s;
    }
}

// ---------------- Layer 1 GEMM via MFMA: 32 nodes/block (proven R12) ----------------
__global__ __launch_bounds__(256, 2)
void k_gemm1(const float* __restrict__ x, const bf16* __restrict__ wt1,
             const float* __restrict__ aw_s, const float* __restrict__ aw_d,
             bf16* __restrict__ h1, float* __restrict__ as1,
             float* __restrict__ ad1) {
    int n0 = blockIdx.x * 32;
    int t = threadIdx.x;
    __shared__ bf16 xs[32 * 136];
    for (int i = 0; i < 4; i++) {
        int idx = t + 256 * i;
        int r = idx >> 5, c4 = idx & 31;
        float4 v = make_float4(0.f, 0.f, 0.f, 0.f);
        if (n0 + r < NN) v = *(const float4*)(x + (size_t)(n0 + r) * 128 + c4 * 4);
        ushort4 o;
        o.x = f2bfbits(v.x); o.y = f2bfbits(v.y);
        o.z = f2bfbits(v.z); o.w = f2bfbits(v.w);
        *(ushort4*)(&xs[r * 136 + c4 * 4]) = o;
    }
    __syncthreads();

    int wv = t >> 6, lane = t & 63;
    int q = lane >> 4, r16 = lane & 15;
    int rowBase = (wv & 1) * 16;
    int colBase = (wv >> 1) * 128;

    f32x4 acc[8];
#pragma unroll
    for (int ct = 0; ct < 8; ct++) acc[ct] = (f32x4){0.f, 0.f, 0.f, 0.f};

#pragma unroll
    for (int kt = 0; kt < 4; kt++) {
        v8bf va = *(const v8bf*)(&xs[(rowBase + r16) * 136 + kt * 32 + q * 8]);
#pragma unroll
        for (int ct = 0; ct < 8; ct++) {
            v8bf vb = *(const v8bf*)(wt1 + (size_t)(colBase + ct * 16 + r16) * 128 + kt * 32 + q * 8);
            acc[ct] = __builtin_amdgcn_mfma_f32_16x16x32_bf16(va, vb, acc[ct], 0, 0, 0);
        }
    }

    float wsv[8], wdv[8];
#pragma unroll
    for (int ct = 0; ct < 8; ct++) {
        int col = colBase + ct * 16 + r16;
        wsv[ct] = aw_s[col];
        wdv[ct] = aw_d[col];
    }

    float ps[4][2], pd[4][2];
#pragma unroll
    for (int reg = 0; reg < 4; reg++) {
        ps[reg][0] = 0.f; ps[reg][1] = 0.f;
        pd[reg][0] = 0.f; pd[reg][1] = 0.f;
    }

#pragma unroll
    for (int reg = 0; reg < 4; reg++) {
        int node = n0 + rowBase + q * 4 + reg;
        bool ok = node < NN;
#pragma unroll
        for (int ct = 0; ct < 8; ct++) {
            float v = acc[ct][reg];
            if (ok) h1[(size_t)node * 256 + colBase + ct * 16 + r16] = __float2bfloat16(v);
            ps[reg][ct >> 2] += v * wsv[ct];
            pd[reg][ct >> 2] += v * wdv[ct];
        }
    }

#pragma unroll
    for (int reg = 0; reg < 4; reg++) {
        int node = n0 + rowBase + q * 4 + reg;
        bool ok = node < NN;
#pragma unroll
        for (int lh = 0; lh < 2; lh++) {
            float a = ps[reg][lh], b = pd[reg][lh];
            for (int mask = 1; mask <= 8; mask <<= 1) {
                a += __shfl_xor(a, mask);
                b += __shfl_xor(b, mask);
            }
            if (r16 == 0 && ok) {
                int head = (wv >> 1) * 2 + lh;
                as1[node * 4 + head] = a;
                ad1[node * 4 + head] = b;
            }
        }
    }
}

// ---------------- Layer 1 gather: 2 col-slices/node, single chunk, 32-bit offsets ----------------
__global__ void k_gather1(const int* __restrict__ csrc, const int* __restrict__ deg,
                          const bf16* __restrict__ h1, const float* __restrict__ as1,
                          const float* __restrict__ ad1, const float* __restrict__ b1,
                          bf16* __restrict__ x2) {
    int bid = blockIdx.x;
    int n = bid >> 1, slice = bid & 1;
    int t = threadIdx.x;        // 0..63
    int lh = t >> 5;            // local head (0/1)
    int cnt = min(deg[n], CAP);
    float2 ad = *(const float2*)&ad1[n * 4 + slice * 2];
    __shared__ unsigned int ls[CAP];   // pre-scaled byte offsets (s*512)
    __shared__ float la[CAP * 2];
    const char* h1c = (const char*)h1;
    unsigned int tconst = (unsigned int)(slice * 128 + t * 2) * 2;
    if (t < cnt) {
        int s = csrc[n * CAP + t];
        s = min(max(s, 0), NN - 1);
        ls[t] = (unsigned int)s << 9;
        float2 as = *(const float2*)&as1[s * 4 + slice * 2];
        la[t * 2 + 0] = lrelu_exp(as.x + ad.x);
        la[t * 2 + 1] = lrelu_exp(as.y + ad.y);
    }
    __syncthreads();
    float a0 = 0.f, a1 = 0.f, ssum = 0.f;
    int j = 0;
    for (; j + 3 < cnt; j += 4) {
        unsigned int o0 = ls[j] + tconst, o1 = ls[j + 1] + tconst;
        unsigned int o2 = ls[j + 2] + tconst, o3 = ls[j + 3] + tconst;
        float A0 = la[j * 2 + lh], A1 = la[j * 2 + 2 + lh];
        float A2 = la[j * 2 + 4 + lh], A3 = la[j * 2 + 6 + lh];
        unsigned int u0 = *(const unsigned int*)(h1c + o0);
        unsigned int u1 = *(const unsigned int*)(h1c + o1);
        unsigned int u2 = *(const unsigned int*)(h1c + o2);
        unsigned int u3 = *(const unsigned int*)(h1c + o3);
        ssum += (A0 + A1) + (A2 + A3);
        a0 = fmaf(A0, lo2f(u0), a0); a0 = fmaf(A1, lo2f(u1), a0);
        a0 = fmaf(A2, lo2f(u2), a0); a0 = fmaf(A3, lo2f(u3), a0);
        a1 = fmaf(A0, hi2f(u0), a1); a1 = fmaf(A1, hi2f(u1), a1);
        a1 = fmaf(A2, hi2f(u2), a1); a1 = fmaf(A3, hi2f(u3), a1);
    }
    for (; j < cnt; j++) {
        unsigned int o0 = ls[j] + tconst;
        float A0 = la[j * 2 + lh];
        unsigned int u0 = *(const unsigned int*)(h1c + o0);
        ssum += A0;
        a0 = fmaf(A0, lo2f(u0), a0);
        a1 = fmaf(A0, hi2f(u0), a1);
    }
    float inv = 1.f / fmaxf(ssum, 1e-35f);
    int c = slice * 128 + t * 2;
    float r0 = a0 * inv + b1[c + 0];
    float r1 = a1 * inv + b1[c + 1];
    r0 = r0 > 0.f ? r0 : (__expf(r0) - 1.f);
    r1 = r1 > 0.f ? r1 : (__expf(r1) - 1.f);
    unsigned int packed = (unsigned int)f2bfbits(r0) | ((unsigned int)f2bfbits(r1) << 16);
    *(unsigned int*)((unsigned short*)x2 + (size_t)n * 256 + c) = packed;
}

// ---------------- Layer 2 GEMM via MFMA: 32 nodes/block (R18) ----------------
__global__ __launch_bounds__(256, 2)
void k_gemm2(const bf16* __restrict__ x2, const bf16* __restrict__ wt2,
             const float* __restrict__ aw_s, const float* __restrict__ aw_d,
             bf16* __restrict__ h2, float* __restrict__ as2,
             float* __restrict__ ad2) {
    int n0 = blockIdx.x * 32;
    int t = threadIdx.x;
    __shared__ bf16 xs[32 * 264];
    __shared__ float psPart[32][2];
    __shared__ float pdPart[32][2];
    for (int i = 0; i < 4; i++) {
        int idx = t + 256 * i;
        int r = idx >> 5, c8 = idx & 31;
        uint4 v;
        if (n0 + r < NN) v = *(const uint4*)(x2 + (size_t)(n0 + r) * 256 + c8 * 8);
        else             v = make_uint4(0, 0, 0, 0);
        *(uint4*)(&xs[r * 264 + c8 * 8]) = v;
    }
    __syncthreads();

    int wv = t >> 6, lane = t & 63;
    int q = lane >> 4, r16 = lane & 15;
    int rowBase = (wv & 1) * 16;
    int colBase = (wv >> 1) * 64;

    f32x4 acc[4];
#pragma unroll
    for (int ct = 0; ct < 4; ct++) acc[ct] = (f32x4){0.f, 0.f, 0.f, 0.f};

#pragma unroll
    for (int kt = 0; kt < 8; kt++) {
        v8bf va = *(const v8bf*)(&xs[(rowBase + r16) * 264 + kt * 32 + q * 8]);
#pragma unroll
        for (int ct = 0; ct < 4; ct++) {
            v8bf vb = *(const v8bf*)(wt2 + (size_t)(colBase + ct * 16 + r16) * 256 + kt * 32 + q * 8);
            acc[ct] = __builtin_amdgcn_mfma_f32_16x16x32_bf16(va, vb, acc[ct], 0, 0, 0);
        }
    }

    float wsv[4], wdv[4];
#pragma unroll
    for (int ct = 0; ct < 4; ct++) {
        int col = colBase + ct * 16 + r16;
        wsv[ct] = aw_s[col];
        wdv[ct] = aw_d[col];
    }

#pragma unroll
    for (int reg = 0; reg < 4; reg++) {
        int node = n0 + rowBase + q * 4 + reg;
        bool ok = node < NN;
        float ps = 0.f, pd = 0.f;
#pragma unroll
        for (int ct = 0; ct < 4; ct++) {
            float v = acc[ct][reg];
            if (ok) h2[(size_t)node * 128 + colBase + ct * 16 + r16] = __float2bfloat16(v);
            ps += v * wsv[ct];
            pd += v * wdv[ct];
        }
        for (int mask = 1; mask <= 8; mask <<= 1) {
            ps += __shfl_xor(ps, mask);
            pd += __shfl_xor(pd, mask);
        }
        if (r16 == 0) {
            int li = rowBase + q * 4 + reg;
            psPart[li][wv >> 1] = ps;
            pdPart[li][wv >> 1] = pd;
        }
    }
    __syncthreads();
    if (t < 32) {
        int node = n0 + t;
        if (node < NN) {
            as2[node] = psPart[t][0] + psPart[t][1];
            ad2[node] = pdPart[t][0] + pdPart[t][1];
        }
    }
}

// ---------------- Layer 2 gather: single chunk, 32-bit offsets, bf16 store ----------------
__global__ void k_gather2(const int* __restrict__ csrc, const int* __restrict__ deg,
                          const bf16* __restrict__ h2, const float* __restrict__ as2,
                          const float* __restrict__ ad2, const float* __restrict__ b2,
                          bf16* __restrict__ hf) {
    int n = blockIdx.x;
    int t = threadIdx.x;        // 0..63
    int cnt = min(deg[n], CAP);
    float adn = ad2[n];
    __shared__ unsigned int ls[CAP];   // pre-scaled byte offsets (s*256)
    __shared__ float la[CAP];
    const char* h2c = (const char*)h2;
    unsigned int tconst = (unsigned int)t * 4;
    if (t < cnt) {
        int s = csrc[n * CAP + t];
        s = min(max(s, 0), NN - 1);
        ls[t] = (unsigned int)s << 8;
        la[t] = lrelu_exp(as2[s] + adn);
    }
    __syncthreads();
    float a0 = 0.f, a1 = 0.f, ssum = 0.f;
    int j = 0;
    for (; j + 3 < cnt; j += 4) {
        unsigned int o0 = ls[j] + tconst, o1 = ls[j + 1] + tconst;
        unsigned int o2 = ls[j + 2] + tconst, o3 = ls[j + 3] + tconst;
        float A0 = la[j], A1 = la[j + 1], A2 = la[j + 2], A3 = la[j + 3];
        unsigned int u0 = *(const unsigned int*)(h2c + o0);
        unsigned int u1 = *(const unsigned int*)(h2c + o1);
        unsigned int u2 = *(const unsigned int*)(h2c + o2);
        unsigned int u3 = *(const unsigned int*)(h2c + o3);
        ssum += (A0 + A1) + (A2 + A3);
        a0 = fmaf(A0, lo2f(u0), a0); a0 = fmaf(A1, lo2f(u1), a0);
        a0 = fmaf(A2, lo2f(u2), a0); a0 = fmaf(A3, lo2f(u3), a0);
        a1 = fmaf(A0, hi2f(u0), a1); a1 = fmaf(A1, hi2f(u1), a1);
        a1 = fmaf(A2, hi2f(u2), a1); a1 = fmaf(A3, hi2f(u3), a1);
    }
    for (; j < cnt; j++) {
        unsigned int o0 = ls[j] + tconst;
        float A0 = la[j];
        unsigned int u0 = *(const unsigned int*)(h2c + o0);
        ssum += A0;
        a0 = fmaf(A0, lo2f(u0), a0);
        a1 = fmaf(A0, hi2f(u0), a1);
    }
    float inv = 1.f / fmaxf(ssum, 1e-35f);
    int c = t * 2;
    float r0 = a0 * inv + b2[c + 0];
    float r1 = a1 * inv + b2[c + 1];
    r0 = r0 > 0.f ? r0 : (__expf(r0) - 1.f);
    r1 = r1 > 0.f ? r1 : (__expf(r1) - 1.f);
    unsigned int packed = (unsigned int)f2bfbits(r0) | ((unsigned int)f2bfbits(r1) << 16);
    *(unsigned int*)((unsigned short*)hf + (size_t)n * 128 + c) = packed;
}

// ---------------- fused mean-pool + linear + sigmoid (batch SORTED; bf16 input) ----------------
__global__ void k_pool(const bf16* __restrict__ hf, const int* __restrict__ batch,
                       const float* __restrict__ Wl, const float* __restrict__ bl,
                       float* __restrict__ out) {
    int b = blockIdx.x;   // 0..511
    int t = threadIdx.x;  // 0..127
    int lo = 0, hi = NN;
    while (lo < hi) { int m = (lo + hi) >> 1; if (batch[m] < b) lo = m + 1; else hi = m; }
    int start = lo;
    int lo2 = start, hi2 = NN;
    while (lo2 < hi2) { int m = (lo2 + hi2) >> 1; if (batch[m] < b + 1) lo2 = m + 1; else hi2 = m; }
    int end = lo2;
    const unsigned short* hu = (const unsigned short*)hf;
    float sum = 0.f;
    for (int n = start; n < end; n++) sum += us2f(hu[(size_t)n * 128 + t]);
    int c = end - start;
    float g = sum / (float)(c > 0 ? c : 1);
    float p = g * Wl[t];
    for (int o = 32; o > 0; o >>= 1) p += __shfl_down(p, o);
    __shared__ float red[2];
    if ((t & 63) == 0) red[t >> 6] = p;
    __syncthreads();
    if (t == 0) {
        float acc = red[0] + red[1] + bl[0];
        out[b] = 1.f / (1.f + __expf(-acc));
    }
}

extern "C" void kernel_launch(void* const* d_in, const int* in_sizes, int n_in,
                              void* d_out, int out_size, void* d_ws, size_t ws_size,
                              hipStream_t stream) {
    const float* x = (const float*)d_in[0];
    const int* ei = (const int*)d_in[1];
    const int* batch = (const int*)d_in[2];
    const float* W1 = (const float*)d_in[3];
    const float* aw_s1 = (const float*)d_in[4];
    const float* aw_d1 = (const float*)d_in[5];
    const float* b1 = (const float*)d_in[6];
    const float* W2 = (const float*)d_in[7];
    const float* aw_s2 = (const float*)d_in[8];
    const float* aw_d2 = (const float*)d_in[9];
    const float* b2 = (const float*)d_in[10];
    const float* Wl = (const float*)d_in[11];
    const float* bl = (const float*)d_in[12];
    const int* srcArr = ei;
    const int* dstArr = ei + EE;

    char* w = (char*)d_ws;
    size_t off = 0;
    auto alloc = [&](size_t bytes) -> void* {
        void* p = (void*)(w + off);
        off = (off + bytes + 255) & ~(size_t)255;
        return p;
    };
    bf16* bufA = (bf16*)alloc((size_t)NN * 256 * 2);   // h1; later h2
    bf16* bufB = (bf16*)alloc((size_t)NN * 256 * 2);   // x2; later hf (bf16 [NN,128])
    int* csrc = (int*)alloc((size_t)NN * CAP * 4);     // 12.8 MB
    float* as1 = (float*)alloc((size_t)NN * 4 * 4);
    float* ad1 = (float*)alloc((size_t)NN * 4 * 4);
    float* as2 = (float*)alloc((size_t)NN * 4);
    float* ad2 = (float*)alloc((size_t)NN * 4);
    int* deg = (int*)alloc((size_t)NN * 4);
    bf16* wt1 = (bf16*)alloc((size_t)256 * 128 * 2);
    bf16* wt2 = (bf16*)alloc((size_t)128 * 256 * 2);
    (void)ws_size;

    k_prep<<<256, 256, 0, stream>>>(W1, W2, wt1, wt2, deg);
    // partitioned scatter: NPART interleaved block groups over edge chunks
    int chunks = (ETOT + 255) / 256;
    k_scatter<<<chunks * NPART, 256, 0, stream>>>(srcArr, dstArr, deg, csrc);

    bf16* h1 = bufA;
    bf16* x2 = bufB;
    k_gemm1<<<(NN + 31) / 32, 256, 0, stream>>>(x, wt1, aw_s1, aw_d1, h1, as1, ad1);
    k_gather1<<<NN * 2, 64, 0, stream>>>(csrc, deg, h1, as1, ad1, b1, x2);

    bf16* h2 = bufA;  // h1 dead after gather1
    k_gemm2<<<(NN + 31) / 32, 256, 0, stream>>>(x2, wt2, aw_s2, aw_d2, h2, as2, ad2);

    bf16* hf = bufB;  // x2 dead after gemm2
    k_gather2<<<NN, 64, 0, stream>>>(csrc, deg, h2, as2, ad2, b2, hf);

    k_pool<<<BB, 128, 0, stream>>>(hf, batch, Wl, bl, (float*)d_out);
}